// Round 7
// baseline (226.195 us; speedup 1.0000x reference)
//
#include <hip/hip_runtime.h>
#include <hip/hip_bf16.h>
#include <cstdint>

// Problem: B=4, S=2048, H=16, D=64, OUT=1024
// q = query @ Wq[h]^T ; scores = q k^T / 8 ; attn = softmax ; o = attn v
// x = concat heads ; out = x @ Wo^T
//
// ws layout (bytes):
//   Qp  [BH][S][D] bf16  @ 0      (pre-scaled by LOG2E/8: scores in log2 units)
//   Kp  [BH][S][D] bf16  @ 16 MiB
//   Vt  [BH][D][S] bf16  @ 32 MiB (transposed)
//   Xb  [B][S][H*D] bf16 @ 48 MiB (attn output)
//   Wob [OUT][H*D] bf16  @ 64 MiB
//
// LDS tiles use SEG-MAJOR layout: off(row,seg) = seg*(ROWS*16) + row*16.
// Fragment reads are then contiguous-by-lane (bank = f(row)) -> conflict-free
// b128 reads; global_load_lds dest = seg block (uniform) + lane*16 (row).

#define QSCALE 0.1803368801111204f   /* (1/8) * log2(e) */

typedef __attribute__((ext_vector_type(8))) short bf16x8;
typedef __attribute__((ext_vector_type(2))) float f32x2;
typedef __attribute__((ext_vector_type(4))) float f32x4;
typedef __attribute__((ext_vector_type(16))) float f32x16;

typedef __attribute__((address_space(1))) unsigned int g_u32;
typedef __attribute__((address_space(3))) unsigned int l_u32;

__device__ inline unsigned cvt_pk_bf16(float a, float b) {
    unsigned r;
    asm("v_cvt_pk_bf16_f32 %0, %1, %2" : "=v"(r) : "v"(a), "v"(b));
    return r;  // low16 = bf16(a), high16 = bf16(b)
}

__device__ inline unsigned short f2bf1(float x) {   // single f32->bf16 (RNE)
    return (unsigned short)cvt_pk_bf16(x, x);
}

__device__ inline uint2 pack4(float a, float b, float c, float d) {
    uint2 u; u.x = cvt_pk_bf16(a, b); u.y = cvt_pk_bf16(c, d); return u;
}

__device__ inline f32x4 mfma16(bf16x8 a, bf16x8 b, f32x4 c) {
    return __builtin_amdgcn_mfma_f32_16x16x32_bf16(a, b, c, 0, 0, 0);
}
__device__ inline f32x16 mfma32(bf16x8 a, bf16x8 b, f32x16 c) {
    return __builtin_amdgcn_mfma_f32_32x32x16_bf16(a, b, c, 0, 0, 0);
}

__device__ inline float sum16v(const f32x16& v) {   // pairwise tree (pk-able)
    const f32x2* p = reinterpret_cast<const f32x2*>(&v);
    f32x2 q0 = p[0] + p[1], q1 = p[2] + p[3], q2 = p[4] + p[5], q3 = p[6] + p[7];
    f32x2 r0 = q0 + q1, r1 = q2 + q3;
    f32x2 t = r0 + r1;
    return t[0] + t[1];
}

// ---------------------------------------------------------------- Wo -> bf16
__global__ __launch_bounds__(256) void wo_conv(const float* __restrict__ Wo,
                                               unsigned short* __restrict__ Wob) {
    int i = (blockIdx.x * 256 + threadIdx.x) * 8;
    float4 f0 = *reinterpret_cast<const float4*>(Wo + i);
    float4 f1 = *reinterpret_cast<const float4*>(Wo + i + 4);
    uint4 h;
    h.x = cvt_pk_bf16(f0.x, f0.y); h.y = cvt_pk_bf16(f0.z, f0.w);
    h.z = cvt_pk_bf16(f1.x, f1.y); h.w = cvt_pk_bf16(f1.z, f1.w);
    *reinterpret_cast<uint4*>(Wob + i) = h;
}

// ------------------------------------------------------------ QKV projection
// fp32 inputs, convert during LDS staging (cvt_pk). z=0: Q (scaled LOG2E/8),
// z=1: K (both swapped-operand -> uint2 stores), z=2: V ([D][S] transpose)
__global__ __launch_bounds__(256) void qkv_proj(
    const float* __restrict__ q_in, const float* __restrict__ k_in,
    const float* __restrict__ v_in,
    const float* __restrict__ Wq, const float* __restrict__ Wk,
    const float* __restrict__ Wv,
    unsigned short* __restrict__ Qp, unsigned short* __restrict__ Kp,
    unsigned short* __restrict__ Vt) {
    const int z = blockIdx.z;
    const float* X = (z == 0) ? q_in : (z == 1) ? k_in : v_in;
    const float* W = (z == 0) ? Wq : (z == 1) ? Wk : Wv;
    const int bh = blockIdx.y;
    const int b = bh >> 4, h = bh & 15;
    const int s0 = blockIdx.x * 64;
    const int t = threadIdx.x;
    const int w = t >> 6, l = t & 63, lr = l & 15, lg = l >> 4;

    __shared__ unsigned short Xs[64][72];
    __shared__ unsigned short Ws[64][72];

    {
        const float* src = X + (size_t)(b * 2048 + s0) * 64;
        const float* wsrc = W + (size_t)h * 4096;
#pragma unroll
        for (int i = 0; i < 4; ++i) {
            int idx = t + i * 256;            // 0..1023
            int r = idx >> 4, c4 = (idx & 15) * 4;
            float4 f = *reinterpret_cast<const float4*>(src + r * 64 + c4);
            *reinterpret_cast<uint2*>(&Xs[r][c4]) = pack4(f.x, f.y, f.z, f.w);
            float4 g = *reinterpret_cast<const float4*>(wsrc + r * 64 + c4);
            *reinterpret_cast<uint2*>(&Ws[r][c4]) = pack4(g.x, g.y, g.z, g.w);
        }
    }
    __syncthreads();

    f32x4 acc[4];
#pragma unroll
    for (int nt = 0; nt < 4; ++nt) acc[nt] = f32x4{0.f, 0.f, 0.f, 0.f};

    const size_t bhS = (size_t)bh * 2048 * 64;
    if (z < 2) {
        // C[e][s]: A = W rows (e), B = X rows (s)
#pragma unroll
        for (int kk = 0; kk < 2; ++kk) {
            bf16x8 a = *reinterpret_cast<const bf16x8*>(&Xs[w * 16 + lr][kk * 32 + lg * 8]);
#pragma unroll
            for (int nt = 0; nt < 4; ++nt) {
                bf16x8 bb = *reinterpret_cast<const bf16x8*>(&Ws[nt * 16 + lr][kk * 32 + lg * 8]);
                acc[nt] = mfma16(bb, a, acc[nt]);
            }
        }
        unsigned short* Out = (z == 0) ? Qp : Kp;
        const float scale = (z == 0) ? QSCALE : 1.0f;
        const int s = s0 + w * 16 + lr;
#pragma unroll
        for (int nt = 0; nt < 4; ++nt) {
            *reinterpret_cast<uint2*>(&Out[bhS + (size_t)s * 64 + nt * 16 + lg * 4]) =
                pack4(acc[nt][0] * scale, acc[nt][1] * scale,
                      acc[nt][2] * scale, acc[nt][3] * scale);
        }
    } else {
        // C[s][e]: A = X rows (s), B = W rows (e); store Vt[e][s..s+3]
#pragma unroll
        for (int kk = 0; kk < 2; ++kk) {
            bf16x8 a = *reinterpret_cast<const bf16x8*>(&Xs[w * 16 + lr][kk * 32 + lg * 8]);
#pragma unroll
            for (int nt = 0; nt < 4; ++nt) {
                bf16x8 bb = *reinterpret_cast<const bf16x8*>(&Ws[nt * 16 + lr][kk * 32 + lg * 8]);
                acc[nt] = mfma16(a, bb, acc[nt]);
            }
        }
#pragma unroll
        for (int nt = 0; nt < 4; ++nt) {
            int e = nt * 16 + lr;
            int s = s0 + w * 16 + lg * 4;
            *reinterpret_cast<uint2*>(&Vt[(size_t)bh * 64 * 2048 + (size_t)e * 2048 + s]) =
                pack4(acc[nt][0], acc[nt][1], acc[nt][2], acc[nt][3]);
        }
    }
}

// ------------------------------------------------------------ flash attention
// 4 waves x 32 q-rows (swapped QK^T, 32x32x16). Two 32-row halves per K-tile.
// P in registers (cvt_pk + permlane32_swap). K/V double-buffered, SEG-MAJOR
// LDS (conflict-free b128 reads). m fixed 0 (scores in log2 units). XCD
// swizzle: bh = id&63 -> all q-blocks of a head on one XCD (K/V L2-hit).
__global__ __launch_bounds__(256, 4) void attn_kernel(
    const unsigned short* __restrict__ Qp, const unsigned short* __restrict__ Kp,
    const unsigned short* __restrict__ Vt, unsigned short* __restrict__ Xb) {
    const int id = blockIdx.x + 16 * blockIdx.y;
    const int bh = id & 63;              // id%8 = bh%8 -> per-XCD head grouping
    const int qx = id >> 6;
    const int b = bh >> 4, h = bh & 15;
    const int t = threadIdx.x;
    const int w = t >> 6, l = t & 63;
    const int lo = l & 31, hi = l >> 5;
    const int qw = qx * 128 + w * 32;

    __shared__ unsigned short Kbuf[2][4096];   // seg-major: seg*1024 + row*16 bytes
    __shared__ unsigned short Vbuf[2][4096];   // seg-major (e-row, k-seg)

    // Q fragments (B-operand): lane lo -> q row qw+lo; d = 16*ds + 8*hi + j
    bf16x8 bq[4];
    {
        const unsigned short* qptr = Qp + ((size_t)bh * 2048 + qw + lo) * 64 + hi * 8;
#pragma unroll
        for (int ds = 0; ds < 4; ++ds)
            bq[ds] = *reinterpret_cast<const bf16x8*>(qptr + ds * 16);
    }

    f32x16 oacc0, oacc1;
#pragma unroll
    for (int r = 0; r < 16; ++r) { oacc0[r] = 0.f; oacc1[r] = 0.f; }
    float lsum = 0.f;

    const unsigned short* kbase = Kp + (size_t)bh * 2048 * 64;
    const unsigned short* vbase = Vt + (size_t)bh * 64 * 2048;

    // staging: wave w stages segs {2w, 2w+1} of K and V; lane = row.
    const int sA = 2 * w, sB = 2 * w + 1;

    // prologue: tile 0
    {
        __builtin_amdgcn_global_load_lds((const g_u32*)(kbase + (size_t)l * 64 + sA * 8),
                                         (l_u32*)((char*)Kbuf[0] + sA * 1024), 16, 0, 0);
        __builtin_amdgcn_global_load_lds((const g_u32*)(kbase + (size_t)l * 64 + sB * 8),
                                         (l_u32*)((char*)Kbuf[0] + sB * 1024), 16, 0, 0);
        __builtin_amdgcn_global_load_lds((const g_u32*)(vbase + (size_t)l * 2048 + sA * 8),
                                         (l_u32*)((char*)Vbuf[0] + sA * 1024), 16, 0, 0);
        __builtin_amdgcn_global_load_lds((const g_u32*)(vbase + (size_t)l * 2048 + sB * 8),
                                         (l_u32*)((char*)Vbuf[0] + sB * 1024), 16, 0, 0);
    }
    __syncthreads();

    for (int kt = 0; kt < 32; ++kt) {
        const int cur = kt & 1;
        if (kt < 31) {   // issue next tile into other buffer; drains at barrier
            const unsigned short* kn = kbase + (size_t)(kt + 1) * 64 * 64;
            const unsigned short* vn = vbase + (kt + 1) * 64;
            __builtin_amdgcn_global_load_lds((const g_u32*)(kn + (size_t)l * 64 + sA * 8),
                                             (l_u32*)((char*)Kbuf[cur ^ 1] + sA * 1024), 16, 0, 0);
            __builtin_amdgcn_global_load_lds((const g_u32*)(kn + (size_t)l * 64 + sB * 8),
                                             (l_u32*)((char*)Kbuf[cur ^ 1] + sB * 1024), 16, 0, 0);
            __builtin_amdgcn_global_load_lds((const g_u32*)(vn + (size_t)l * 2048 + sA * 8),
                                             (l_u32*)((char*)Vbuf[cur ^ 1] + sA * 1024), 16, 0, 0);
            __builtin_amdgcn_global_load_lds((const g_u32*)(vn + (size_t)l * 2048 + sB * 8),
                                             (l_u32*)((char*)Vbuf[cur ^ 1] + sB * 1024), 16, 0, 0);
        }

        const char* kb = (const char*)Kbuf[cur];
        const char* vb = (const char*)Vbuf[cur];

#pragma unroll
        for (int half = 0; half < 2; ++half) {
            // ---- swapped QK^T for 32 K-rows: C[k][q], q = lo lane-local
            f32x16 s;
#pragma unroll
            for (int r = 0; r < 16; ++r) s[r] = 0.f;
            __builtin_amdgcn_s_setprio(1);
#pragma unroll
            for (int ds = 0; ds < 4; ++ds) {
                bf16x8 ka = *reinterpret_cast<const bf16x8*>(
                    kb + (2 * ds + hi) * 1024 + (lo + 32 * half) * 16);
                s = mfma32(ka, bq[ds], s);
            }
            __builtin_amdgcn_s_setprio(0);

            // ---- p = exp2(s)  (m == 0), pairwise row-sum
#pragma unroll
            for (int r = 0; r < 16; ++r) s[r] = __builtin_amdgcn_exp2f(s[r]);
            lsum += sum16v(s);

            // ---- PA build (cvt_pk + permlane32_swap) + PV
#pragma unroll
            for (int ks2 = 0; ks2 < 2; ++ks2) {
                const int bb = ks2 * 8;
                unsigned w0 = cvt_pk_bf16(s[bb + 0], s[bb + 1]);
                unsigned w1 = cvt_pk_bf16(s[bb + 2], s[bb + 3]);
                unsigned w2 = cvt_pk_bf16(s[bb + 4], s[bb + 5]);
                unsigned w3 = cvt_pk_bf16(s[bb + 6], s[bb + 7]);
                asm("v_permlane32_swap_b32 %0, %1" : "+v"(w0), "+v"(w2));
                asm("v_permlane32_swap_b32 %0, %1" : "+v"(w1), "+v"(w3));
                union { unsigned u[4]; bf16x8 v; } pa;
                pa.u[0] = w0; pa.u[1] = w1; pa.u[2] = w2; pa.u[3] = w3;
                const char* vs = vb + (2 * (2 * half + ks2) + hi) * 1024;
                bf16x8 v0 = *reinterpret_cast<const bf16x8*>(vs + lo * 16);
                bf16x8 v1 = *reinterpret_cast<const bf16x8*>(vs + (lo + 32) * 16);
                __builtin_amdgcn_s_setprio(1);
                oacc0 = mfma32(pa.v, v0, oacc0);
                oacc1 = mfma32(pa.v, v1, oacc1);
                __builtin_amdgcn_s_setprio(0);
            }
        }
        __syncthreads();   // drains vmcnt (next tile landed), syncs buffers
    }

    // epilogue: fold partner half-row sums, divide, store
    lsum += __shfl_xor(lsum, 32);
    const size_t rowbase = (size_t)b * 2048 * 1024 + (size_t)h * 64;
#pragma unroll
    for (int r = 0; r < 16; ++r) {
        int ql = (r & 3) + 8 * (r >> 2) + 4 * hi;
        float inv = 1.0f / __shfl(lsum, ql);
        unsigned short* dst = Xb + rowbase + (size_t)(qw + ql) * 1024;
        dst[lo] = f2bf1(oacc0[r] * inv);
        dst[lo + 32] = f2bf1(oacc1[r] * inv);
    }
}

// ------------------------------------------------------------- output GEMM
// out[M=8192][N=1024] = Xb[M][K=1024] . Wob[N][K]^T
// 128x128 tile, BK=64, double-buffered SEG-MAJOR LDS (conflict-free reads:
// same-address 4-lane broadcast + contiguous rows), stage-early/1-barrier,
// swapped-operand MFMA -> float4 C-stores. XCD swizzle for L2 residency.
__global__ __launch_bounds__(256) void out_gemm(
    const unsigned short* __restrict__ Xb, const unsigned short* __restrict__ Wob,
    float* __restrict__ out) {
    const int wg = blockIdx.x + 8 * blockIdx.y;   // 0..511
    const int xcd = wg & 7, k2 = wg >> 3;         // id%8 XCD round-robin
    const int mb = (xcd * 8 + (k2 & 7)) * 128;
    const int nb = (k2 >> 3) * 128;
    const int t = threadIdx.x;
    const int w = t >> 6, l = t & 63, lr = l & 15, lg = l >> 4;
    const int wr = (w >> 1) * 64, wc = (w & 1) * 64;

    __shared__ unsigned short As[2][8192];   // seg-major: seg*2048 + row*16 bytes
    __shared__ unsigned short Bs[2][8192];

    f32x4 acc[4][4];
#pragma unroll
    for (int mi = 0; mi < 4; ++mi)
#pragma unroll
        for (int ni = 0; ni < 4; ++ni) acc[mi][ni] = f32x4{0.f, 0.f, 0.f, 0.f};

    // staging: wave w stages segs {2w, 2w+1}; 2 half-row issues each (128 rows)
    const int sA = 2 * w, sB = 2 * w + 1;

#pragma unroll
    for (int i = 0; i < 4; ++i) {
        int s = (i & 1) ? sB : sA;
        int hf = i >> 1;
        int r = hf * 64 + l;
        __builtin_amdgcn_global_load_lds(
            (const g_u32*)(Xb + (size_t)(mb + r) * 1024 + s * 8),
            (l_u32*)((char*)As[0] + s * 2048 + hf * 1024), 16, 0, 0);
        __builtin_amdgcn_global_load_lds(
            (const g_u32*)(Wob + (size_t)(nb + r) * 1024 + s * 8),
            (l_u32*)((char*)Bs[0] + s * 2048 + hf * 1024), 16, 0, 0);
    }
    __syncthreads();

    for (int kt = 0; kt < 16; ++kt) {
        const int cur = kt & 1;
        if (kt < 15) {   // stage next tile early; latency hides under MFMA
#pragma unroll
            for (int i = 0; i < 4; ++i) {
                int s = (i & 1) ? sB : sA;
                int hf = i >> 1;
                int r = hf * 64 + l;
                __builtin_amdgcn_global_load_lds(
                    (const g_u32*)(Xb + (size_t)(mb + r) * 1024 + (kt + 1) * 64 + s * 8),
                    (l_u32*)((char*)As[cur ^ 1] + s * 2048 + hf * 1024), 16, 0, 0);
                __builtin_amdgcn_global_load_lds(
                    (const g_u32*)(Wob + (size_t)(nb + r) * 1024 + (kt + 1) * 64 + s * 8),
                    (l_u32*)((char*)Bs[cur ^ 1] + s * 2048 + hf * 1024), 16, 0, 0);
            }
        }

        const char* ab = (const char*)As[cur];
        const char* bbp = (const char*)Bs[cur];
#pragma unroll
        for (int kk = 0; kk < 2; ++kk) {
            const int segb = (4 * kk + lg) * 2048;
            bf16x8 af[4], bf[4];
#pragma unroll
            for (int mi = 0; mi < 4; ++mi)
                af[mi] = *reinterpret_cast<const bf16x8*>(ab + segb + (wr + mi * 16 + lr) * 16);
#pragma unroll
            for (int ni = 0; ni < 4; ++ni)
                bf[ni] = *reinterpret_cast<const bf16x8*>(bbp + segb + (wc + ni * 16 + lr) * 16);
            __builtin_amdgcn_s_setprio(1);
#pragma unroll
            for (int mi = 0; mi < 4; ++mi)
#pragma unroll
                for (int ni = 0; ni < 4; ++ni)
                    acc[mi][ni] = mfma16(bf[ni], af[mi], acc[mi][ni]);
            __builtin_amdgcn_s_setprio(0);
        }
        __syncthreads();
    }

    // C[n][m]: row = n-local = 4lg+j, col = m-local = lr  ->  float4 along n
#pragma unroll
    for (int mi = 0; mi < 4; ++mi) {
        const size_t row = (size_t)(mb + wr + mi * 16 + lr);
#pragma unroll
        for (int ni = 0; ni < 4; ++ni) {
            float4 o;
            o.x = acc[mi][ni][0]; o.y = acc[mi][ni][1];
            o.z = acc[mi][ni][2]; o.w = acc[mi][ni][3];
            *reinterpret_cast<float4*>(&out[row * 1024 + nb + wc + ni * 16 + lg * 4]) = o;
        }
    }
}

// ---------------------------------------------------------------- launcher
extern "C" void kernel_launch(void* const* d_in, const int* in_sizes, int n_in,
                              void* d_out, int out_size, void* d_ws, size_t ws_size,
                              hipStream_t stream) {
    (void)in_sizes; (void)n_in; (void)out_size; (void)ws_size;
    const float* query = (const float*)d_in[0];
    const float* key   = (const float*)d_in[1];
    const float* value = (const float*)d_in[2];
    const float* Wq = (const float*)d_in[3];
    const float* Wk = (const float*)d_in[4];
    const float* Wv = (const float*)d_in[5];
    const float* Wo = (const float*)d_in[6];
    float* out = (float*)d_out;

    char* ws = (char*)d_ws;
    unsigned short* Qp  = (unsigned short*)(ws);
    unsigned short* Kp  = (unsigned short*)(ws + (size_t)16 * 1024 * 1024);
    unsigned short* Vt  = (unsigned short*)(ws + (size_t)32 * 1024 * 1024);
    unsigned short* Xb  = (unsigned short*)(ws + (size_t)48 * 1024 * 1024);
    unsigned short* Wob = (unsigned short*)(ws + (size_t)64 * 1024 * 1024);

    hipLaunchKernelGGL(wo_conv, dim3(512), dim3(256), 0, stream, Wo, Wob);
    hipLaunchKernelGGL(qkv_proj, dim3(32, 64, 3), dim3(256), 0, stream,
                       query, key, value, Wq, Wk, Wv, Qp, Kp, Vt);
    hipLaunchKernelGGL(attn_kernel, dim3(16, 64), dim3(256), 0, stream,
                       Qp, Kp, Vt, Xb);
    hipLaunchKernelGGL(out_gemm, dim3(8, 64), dim3(256), 0, stream,
                       Xb, Wob, out);
}

// Round 8
// 207.417 us; speedup vs baseline: 1.0905x; 1.0905x over previous
//
#include <hip/hip_runtime.h>
#include <hip/hip_bf16.h>
#include <cstdint>

// Problem: B=4, S=2048, H=16, D=64, OUT=1024
// q = query @ Wq[h]^T ; scores = q k^T / 8 ; attn = softmax ; o = attn v
// x = concat heads ; out = x @ Wo^T
//
// ws layout (bytes):
//   Qp  [BH][S][D] bf16  @ 0      (pre-scaled by LOG2E/8: scores in log2 units)
//   Kp  [BH][S][D] bf16  @ 16 MiB
//   Vt  [BH][D][S] bf16  @ 32 MiB (transposed)
//   Xb  [B][S][H*D] bf16 @ 48 MiB (attn output)
//   Wob [OUT][H*D] bf16  @ 64 MiB
//   Wqb/Wkb/Wvb bf16     @ 66 MiB (128 KiB each)

#define QSCALE 0.1803368801111204f   /* (1/8) * log2(e) */

typedef __attribute__((ext_vector_type(8))) short bf16x8;
typedef __attribute__((ext_vector_type(2))) float f32x2;
typedef __attribute__((ext_vector_type(4))) float f32x4;
typedef __attribute__((ext_vector_type(16))) float f32x16;

typedef __attribute__((address_space(1))) unsigned int g_u32;
typedef __attribute__((address_space(3))) unsigned int l_u32;

__device__ inline unsigned cvt_pk_bf16(float a, float b) {
    unsigned r;
    asm("v_cvt_pk_bf16_f32 %0, %1, %2" : "=v"(r) : "v"(a), "v"(b));
    return r;  // low16 = bf16(a), high16 = bf16(b)
}

__device__ inline unsigned short f2bf1(float x) {   // single f32->bf16 (RNE)
    return (unsigned short)cvt_pk_bf16(x, x);
}

__device__ inline uint2 pack4(float a, float b, float c, float d) {
    uint2 u; u.x = cvt_pk_bf16(a, b); u.y = cvt_pk_bf16(c, d); return u;
}

__device__ inline f32x4 mfma16(bf16x8 a, bf16x8 b, f32x4 c) {
    return __builtin_amdgcn_mfma_f32_16x16x32_bf16(a, b, c, 0, 0, 0);
}
__device__ inline f32x16 mfma32(bf16x8 a, bf16x8 b, f32x16 c) {
    return __builtin_amdgcn_mfma_f32_32x32x16_bf16(a, b, c, 0, 0, 0);
}

__device__ inline float sum16v(const f32x16& v) {   // pairwise tree (pk-able)
    const f32x2* p = reinterpret_cast<const f32x2*>(&v);
    f32x2 q0 = p[0] + p[1], q1 = p[2] + p[3], q2 = p[4] + p[5], q3 = p[6] + p[7];
    f32x2 r0 = q0 + q1, r1 = q2 + q3;
    f32x2 t = r0 + r1;
    return t[0] + t[1];
}

// ------------------------------------------- all weight fp32->bf16 conversions
__global__ __launch_bounds__(256) void wconv(
    const float* __restrict__ wo, const float* __restrict__ wq,
    const float* __restrict__ wk, const float* __restrict__ wv,
    unsigned short* __restrict__ wob, unsigned short* __restrict__ wqb,
    unsigned short* __restrict__ wkb, unsigned short* __restrict__ wvb) {
    const int y = blockIdx.y;
    const float* src = (y == 0) ? wo : (y == 1) ? wq : (y == 2) ? wk : wv;
    unsigned short* dst = (y == 0) ? wob : (y == 1) ? wqb : (y == 2) ? wkb : wvb;
    const int n = (y == 0) ? 1048576 : 65536;
    int i = (blockIdx.x * 256 + threadIdx.x) * 8;
    if (i >= n) return;
    float4 f0 = *reinterpret_cast<const float4*>(src + i);
    float4 f1 = *reinterpret_cast<const float4*>(src + i + 4);
    uint4 h;
    h.x = cvt_pk_bf16(f0.x, f0.y); h.y = cvt_pk_bf16(f0.z, f0.w);
    h.z = cvt_pk_bf16(f1.x, f1.y); h.w = cvt_pk_bf16(f1.z, f1.w);
    *reinterpret_cast<uint4*>(dst + i) = h;
}

// ------------------------------------------------------------ QKV projection
// Head-looped: block = 128 s-rows x one z. X staged+converted ONCE, X frags
// hoisted to regs, then 16 heads stream W frags from L2 (bf16, 128KB/z).
// z=0: Q (scaled LOG2E/8) / z=1: K  -> C[e][s] (A=W) -> uint2 e-contiguous.
// z=2: V -> C[s][e] (A=X) -> Vt[e][s] uint2 s-contiguous.
__global__ __launch_bounds__(256) void qkv_proj(
    const float* __restrict__ q_in, const float* __restrict__ k_in,
    const float* __restrict__ v_in,
    const unsigned short* __restrict__ Wqb, const unsigned short* __restrict__ Wkb,
    const unsigned short* __restrict__ Wvb,
    unsigned short* __restrict__ Qp, unsigned short* __restrict__ Kp,
    unsigned short* __restrict__ Vt) {
    const int z = blockIdx.y;
    const float* X = (z == 0) ? q_in : (z == 1) ? k_in : v_in;
    const unsigned short* W = (z == 0) ? Wqb : (z == 1) ? Wkb : Wvb;
    const int srow0 = blockIdx.x * 128;       // global row (b*2048 + s)
    const int b = srow0 >> 11;
    const int sb = srow0 & 2047;
    const int t = threadIdx.x;
    const int w = t >> 6, l = t & 63, lr = l & 15, lg = l >> 4;

    __shared__ unsigned short Xs[128][72];

    {
        const float* src = X + (size_t)srow0 * 64;
#pragma unroll
        for (int i = 0; i < 8; ++i) {
            int idx = t + i * 256;            // 0..2047 float4-groups
            int r = idx >> 4, c4 = (idx & 15) * 4;
            float4 f = *reinterpret_cast<const float4*>(src + r * 64 + c4);
            *reinterpret_cast<uint2*>(&Xs[r][c4]) = pack4(f.x, f.y, f.z, f.w);
        }
    }
    __syncthreads();

    // X fragments (rows indexed by lr within 16-frame): 4 frags, reused 16x
    bf16x8 xf[2][2];
#pragma unroll
    for (int sf = 0; sf < 2; ++sf)
#pragma unroll
        for (int kk = 0; kk < 2; ++kk)
            xf[sf][kk] = *reinterpret_cast<const bf16x8*>(&Xs[w * 32 + sf * 16 + lr][kk * 32 + lg * 8]);

    for (int h = 0; h < 16; ++h) {
        const unsigned short* Wh = W + h * 4096;
        bf16x8 wf[4][2];
#pragma unroll
        for (int nt = 0; nt < 4; ++nt)
#pragma unroll
            for (int kk = 0; kk < 2; ++kk)
                wf[nt][kk] = *reinterpret_cast<const bf16x8*>(Wh + (nt * 16 + lr) * 64 + kk * 32 + lg * 8);

        const size_t bhS = (size_t)(b * 16 + h) * 2048 * 64;
        f32x4 acc[4][2];
#pragma unroll
        for (int nt = 0; nt < 4; ++nt)
#pragma unroll
            for (int sf = 0; sf < 2; ++sf) acc[nt][sf] = f32x4{0.f, 0.f, 0.f, 0.f};

        if (z < 2) {
            // C[e][s]: A = W (e rows), B = X (s rows)
#pragma unroll
            for (int kk = 0; kk < 2; ++kk)
#pragma unroll
                for (int nt = 0; nt < 4; ++nt)
#pragma unroll
                    for (int sf = 0; sf < 2; ++sf)
                        acc[nt][sf] = mfma16(wf[nt][kk], xf[sf][kk], acc[nt][sf]);
            unsigned short* Out = (z == 0) ? Qp : Kp;
            const float scale = (z == 0) ? QSCALE : 1.0f;
#pragma unroll
            for (int nt = 0; nt < 4; ++nt)
#pragma unroll
                for (int sf = 0; sf < 2; ++sf) {
                    int s = sb + w * 32 + sf * 16 + lr;
                    int e0 = nt * 16 + lg * 4;
                    *reinterpret_cast<uint2*>(&Out[bhS + (size_t)s * 64 + e0]) =
                        pack4(acc[nt][sf][0] * scale, acc[nt][sf][1] * scale,
                              acc[nt][sf][2] * scale, acc[nt][sf][3] * scale);
                }
        } else {
            // C[s][e]: A = X (s rows), B = W (e rows) -> Vt[e][s..s+3]
#pragma unroll
            for (int kk = 0; kk < 2; ++kk)
#pragma unroll
                for (int nt = 0; nt < 4; ++nt)
#pragma unroll
                    for (int sf = 0; sf < 2; ++sf)
                        acc[nt][sf] = mfma16(xf[sf][kk], wf[nt][kk], acc[nt][sf]);
#pragma unroll
            for (int nt = 0; nt < 4; ++nt)
#pragma unroll
                for (int sf = 0; sf < 2; ++sf) {
                    int e = nt * 16 + lr;
                    int s4 = sb + w * 32 + sf * 16 + lg * 4;
                    *reinterpret_cast<uint2*>(
                        &Vt[(size_t)(b * 16 + h) * 64 * 2048 + (size_t)e * 2048 + s4]) =
                        pack4(acc[nt][sf][0], acc[nt][sf][1], acc[nt][sf][2], acc[nt][sf][3]);
                }
        }
    }
}

// ------------------------------------------------------------ flash attention
// (r6 structure restored verbatim: coalesced row-major staging w/ XOR
// pre-swizzled source; conflicts measured free, gather staging measured bad.)
__global__ __launch_bounds__(256, 4) void attn_kernel(
    const unsigned short* __restrict__ Qp, const unsigned short* __restrict__ Kp,
    const unsigned short* __restrict__ Vt, unsigned short* __restrict__ Xb) {
    const int id = blockIdx.x + 16 * blockIdx.y;
    const int bh = id & 63;              // id%8 = bh%8 -> per-XCD head grouping
    const int qx = id >> 6;
    const int b = bh >> 4, h = bh & 15;
    const int t = threadIdx.x;
    const int w = t >> 6, l = t & 63;
    const int lo = l & 31, hi = l >> 5;
    const int qw = qx * 128 + w * 32;

    __shared__ unsigned short Kbuf[2][4096];   // [64 rows][64 cols], swizzled segs
    __shared__ unsigned short Vbuf[2][4096];   // [64 e-rows][64 k-cols], swizzled

    bf16x8 bq[4];
    {
        const unsigned short* qptr = Qp + ((size_t)bh * 2048 + qw + lo) * 64 + hi * 8;
#pragma unroll
        for (int ds = 0; ds < 4; ++ds)
            bq[ds] = *reinterpret_cast<const bf16x8*>(qptr + ds * 16);
    }

    f32x16 oacc0, oacc1;
#pragma unroll
    for (int r = 0; r < 16; ++r) { oacc0[r] = 0.f; oacc1[r] = 0.f; }
    float lsum = 0.f;

    const unsigned short* kbase = Kp + (size_t)bh * 2048 * 64;
    const unsigned short* vbase = Vt + (size_t)bh * 64 * 2048;

    const int rr = l >> 3;              // 0..7
    const int sp = (l & 7) ^ rr;        // pre-swizzled segment
    const int rb = w * 16;              // wave's 16-row slice

#pragma unroll
    for (int i = 0; i < 2; ++i) {
        int r = rb + i * 8 + rr;
        __builtin_amdgcn_global_load_lds(
            (const g_u32*)(kbase + (size_t)r * 64 + sp * 8),
            (l_u32*)(&Kbuf[0][(rb + i * 8) * 64]), 16, 0, 0);
        __builtin_amdgcn_global_load_lds(
            (const g_u32*)(vbase + (size_t)r * 2048 + sp * 8),
            (l_u32*)(&Vbuf[0][(rb + i * 8) * 64]), 16, 0, 0);
    }
    __syncthreads();

    const int swz = (lo & 7) << 4;

    for (int kt = 0; kt < 32; ++kt) {
        const int cur = kt & 1;
        if (kt < 31) {
#pragma unroll
            for (int i = 0; i < 2; ++i) {
                int r = rb + i * 8 + rr;
                __builtin_amdgcn_global_load_lds(
                    (const g_u32*)(kbase + (size_t)((kt + 1) * 64 + r) * 64 + sp * 8),
                    (l_u32*)(&Kbuf[cur ^ 1][(rb + i * 8) * 64]), 16, 0, 0);
                __builtin_amdgcn_global_load_lds(
                    (const g_u32*)(vbase + (size_t)r * 2048 + (kt + 1) * 64 + sp * 8),
                    (l_u32*)(&Vbuf[cur ^ 1][(rb + i * 8) * 64]), 16, 0, 0);
            }
        }

        const char* kb = (const char*)Kbuf[cur];
        const char* vb = (const char*)Vbuf[cur];

#pragma unroll
        for (int half = 0; half < 2; ++half) {
            f32x16 s;
#pragma unroll
            for (int r = 0; r < 16; ++r) s[r] = 0.f;
            const char* krow = kb + (lo + 32 * half) * 128;
            __builtin_amdgcn_s_setprio(1);
#pragma unroll
            for (int ds = 0; ds < 4; ++ds) {
                bf16x8 ka = *reinterpret_cast<const bf16x8*>(krow + ((32 * ds + 16 * hi) ^ swz));
                s = mfma32(ka, bq[ds], s);
            }
            __builtin_amdgcn_s_setprio(0);

#pragma unroll
            for (int r = 0; r < 16; ++r) s[r] = __builtin_amdgcn_exp2f(s[r]);
            lsum += sum16v(s);

#pragma unroll
            for (int ks2 = 0; ks2 < 2; ++ks2) {
                const int bb = ks2 * 8;
                unsigned w0 = cvt_pk_bf16(s[bb + 0], s[bb + 1]);
                unsigned w1 = cvt_pk_bf16(s[bb + 2], s[bb + 3]);
                unsigned w2 = cvt_pk_bf16(s[bb + 4], s[bb + 5]);
                unsigned w3 = cvt_pk_bf16(s[bb + 6], s[bb + 7]);
                asm("v_permlane32_swap_b32 %0, %1" : "+v"(w0), "+v"(w2));
                asm("v_permlane32_swap_b32 %0, %1" : "+v"(w1), "+v"(w3));
                union { unsigned u[4]; bf16x8 v; } pa;
                pa.u[0] = w0; pa.u[1] = w1; pa.u[2] = w2; pa.u[3] = w3;
                int c = (32 * (half * 2 + ks2) + 16 * hi) ^ swz;
                bf16x8 v0 = *reinterpret_cast<const bf16x8*>(vb + lo * 128 + c);
                bf16x8 v1 = *reinterpret_cast<const bf16x8*>(vb + (lo + 32) * 128 + c);
                __builtin_amdgcn_s_setprio(1);
                oacc0 = mfma32(pa.v, v0, oacc0);
                oacc1 = mfma32(pa.v, v1, oacc1);
                __builtin_amdgcn_s_setprio(0);
            }
        }
        __syncthreads();
    }

    lsum += __shfl_xor(lsum, 32);
    const size_t rowbase = (size_t)b * 2048 * 1024 + (size_t)h * 64;
#pragma unroll
    for (int r = 0; r < 16; ++r) {
        int ql = (r & 3) + 8 * (r >> 2) + 4 * hi;
        float inv = 1.0f / __shfl(lsum, ql);
        unsigned short* dst = Xb + rowbase + (size_t)(qw + ql) * 1024;
        dst[lo] = f2bf1(oacc0[r] * inv);
        dst[lo + 32] = f2bf1(oacc1[r] * inv);
    }
}

// ------------------------------------------------------------- output GEMM
// (r6 structure restored verbatim.)
__global__ __launch_bounds__(256) void out_gemm(
    const unsigned short* __restrict__ Xb, const unsigned short* __restrict__ Wob,
    float* __restrict__ out) {
    const int wg = blockIdx.x + 8 * blockIdx.y;   // 0..511
    const int xcd = wg & 7, k2 = wg >> 3;         // id%8 XCD round-robin
    const int mb = (xcd * 8 + (k2 & 7)) * 128;
    const int nb = (k2 >> 3) * 128;
    const int t = threadIdx.x;
    const int w = t >> 6, l = t & 63, lr = l & 15, lg = l >> 4;
    const int wr = (w >> 1) * 64, wc = (w & 1) * 64;

    __shared__ unsigned short As[2][128 * 64];
    __shared__ unsigned short Bs[2][128 * 64];

    f32x4 acc[4][4];
#pragma unroll
    for (int mi = 0; mi < 4; ++mi)
#pragma unroll
        for (int ni = 0; ni < 4; ++ni) acc[mi][ni] = f32x4{0.f, 0.f, 0.f, 0.f};

    const int rr = l >> 3;
    const int sp = (l & 7) ^ rr;        // pre-swizzled 16B segment
    const int swz = (lr & 7) << 4;

#pragma unroll
    for (int i = 0; i < 4; ++i) {
        int r = w * 32 + i * 8 + rr;
        __builtin_amdgcn_global_load_lds(
            (const g_u32*)(Xb + (size_t)(mb + r) * 1024 + sp * 8),
            (l_u32*)(&As[0][(w * 32 + i * 8) * 64]), 16, 0, 0);
        __builtin_amdgcn_global_load_lds(
            (const g_u32*)(Wob + (size_t)(nb + r) * 1024 + sp * 8),
            (l_u32*)(&Bs[0][(w * 32 + i * 8) * 64]), 16, 0, 0);
    }
    __syncthreads();

    for (int kt = 0; kt < 16; ++kt) {
        const int cur = kt & 1;
        if (kt < 15) {
#pragma unroll
            for (int i = 0; i < 4; ++i) {
                int r = w * 32 + i * 8 + rr;
                __builtin_amdgcn_global_load_lds(
                    (const g_u32*)(Xb + (size_t)(mb + r) * 1024 + (kt + 1) * 64 + sp * 8),
                    (l_u32*)(&As[cur ^ 1][(w * 32 + i * 8) * 64]), 16, 0, 0);
                __builtin_amdgcn_global_load_lds(
                    (const g_u32*)(Wob + (size_t)(nb + r) * 1024 + (kt + 1) * 64 + sp * 8),
                    (l_u32*)(&Bs[cur ^ 1][(w * 32 + i * 8) * 64]), 16, 0, 0);
            }
        }

        const char* ab = (const char*)As[cur];
        const char* bbp = (const char*)Bs[cur];
#pragma unroll
        for (int kk = 0; kk < 2; ++kk) {
            const int cb = (kk * 64 + lg * 16) ^ swz;
            bf16x8 af[4], bf[4];
#pragma unroll
            for (int mi = 0; mi < 4; ++mi)
                af[mi] = *reinterpret_cast<const bf16x8*>(ab + (wr + mi * 16 + lr) * 128 + cb);
#pragma unroll
            for (int ni = 0; ni < 4; ++ni)
                bf[ni] = *reinterpret_cast<const bf16x8*>(bbp + (wc + ni * 16 + lr) * 128 + cb);
            __builtin_amdgcn_s_setprio(1);
#pragma unroll
            for (int mi = 0; mi < 4; ++mi)
#pragma unroll
                for (int ni = 0; ni < 4; ++ni)
                    acc[mi][ni] = mfma16(bf[ni], af[mi], acc[mi][ni]);
            __builtin_amdgcn_s_setprio(0);
        }
        __syncthreads();
    }

#pragma unroll
    for (int mi = 0; mi < 4; ++mi) {
        const size_t row = (size_t)(mb + wr + mi * 16 + lr);
#pragma unroll
        for (int ni = 0; ni < 4; ++ni) {
            float4 o;
            o.x = acc[mi][ni][0]; o.y = acc[mi][ni][1];
            o.z = acc[mi][ni][2]; o.w = acc[mi][ni][3];
            *reinterpret_cast<float4*>(&out[row * 1024 + nb + wc + ni * 16 + lg * 4]) = o;
        }
    }
}

// ---------------------------------------------------------------- launcher
extern "C" void kernel_launch(void* const* d_in, const int* in_sizes, int n_in,
                              void* d_out, int out_size, void* d_ws, size_t ws_size,
                              hipStream_t stream) {
    (void)in_sizes; (void)n_in; (void)out_size; (void)ws_size;
    const float* query = (const float*)d_in[0];
    const float* key   = (const float*)d_in[1];
    const float* value = (const float*)d_in[2];
    const float* Wq = (const float*)d_in[3];
    const float* Wk = (const float*)d_in[4];
    const float* Wv = (const float*)d_in[5];
    const float* Wo = (const float*)d_in[6];
    float* out = (float*)d_out;

    char* ws = (char*)d_ws;
    unsigned short* Qp  = (unsigned short*)(ws);
    unsigned short* Kp  = (unsigned short*)(ws + (size_t)16 * 1024 * 1024);
    unsigned short* Vt  = (unsigned short*)(ws + (size_t)32 * 1024 * 1024);
    unsigned short* Xb  = (unsigned short*)(ws + (size_t)48 * 1024 * 1024);
    unsigned short* Wob = (unsigned short*)(ws + (size_t)64 * 1024 * 1024);
    unsigned short* Wqb = (unsigned short*)(ws + (size_t)66 * 1024 * 1024);
    unsigned short* Wkb = Wqb + 65536;
    unsigned short* Wvb = Wkb + 65536;

    hipLaunchKernelGGL(wconv, dim3(512, 4), dim3(256), 0, stream,
                       Wo, Wq, Wk, Wv, Wob, Wqb, Wkb, Wvb);
    hipLaunchKernelGGL(qkv_proj, dim3(64, 3), dim3(256), 0, stream,
                       query, key, value, Wqb, Wkb, Wvb, Qp, Kp, Vt);
    hipLaunchKernelGGL(attn_kernel, dim3(16, 64), dim3(256), 0, stream,
                       Qp, Kp, Vt, Xb);
    hipLaunchKernelGGL(out_gemm, dim3(8, 64), dim3(256), 0, stream,
                       Xb, Wob, out);
}

// Round 10
// 199.501 us; speedup vs baseline: 1.1338x; 1.0397x over previous
//
#include <hip/hip_runtime.h>
#include <hip/hip_bf16.h>
#include <cstdint>

// Problem: B=4, S=2048, H=16, D=64, OUT=1024
// q = query @ Wq[h]^T ; scores = q k^T / 8 ; attn = softmax ; o = attn v
// x = concat heads ; out = x @ Wo^T
//
// ws layout (bytes):
//   Qp  [BH][S][D] bf16  @ 0      (pre-scaled by LOG2E/8: scores in log2 units)
//   Kp  [BH][S][D] bf16  @ 16 MiB
//   Vt  [BH][D][S] bf16  @ 32 MiB (transposed)
//   Xb  [B][S][H*D] bf16 @ 48 MiB (attn output)
//   Wob [OUT][H*D] bf16  @ 64 MiB

#define QSCALE 0.1803368801111204f   /* (1/8) * log2(e) */

typedef __attribute__((ext_vector_type(8))) short bf16x8;
typedef __attribute__((ext_vector_type(2))) float f32x2;
typedef __attribute__((ext_vector_type(4))) float f32x4;
typedef __attribute__((ext_vector_type(16))) float f32x16;

typedef __attribute__((address_space(1))) unsigned int g_u32;
typedef __attribute__((address_space(3))) unsigned int l_u32;

__device__ inline unsigned cvt_pk_bf16(float a, float b) {
    unsigned r;
    asm("v_cvt_pk_bf16_f32 %0, %1, %2" : "=v"(r) : "v"(a), "v"(b));
    return r;  // low16 = bf16(a), high16 = bf16(b)
}

__device__ inline unsigned short f2bf1(float x) {   // single f32->bf16 (RNE)
    return (unsigned short)cvt_pk_bf16(x, x);
}

__device__ inline uint2 pack4(float a, float b, float c, float d) {
    uint2 u; u.x = cvt_pk_bf16(a, b); u.y = cvt_pk_bf16(c, d); return u;
}

__device__ inline f32x4 mfma16(bf16x8 a, bf16x8 b, f32x4 c) {
    return __builtin_amdgcn_mfma_f32_16x16x32_bf16(a, b, c, 0, 0, 0);
}
__device__ inline f32x16 mfma32(bf16x8 a, bf16x8 b, f32x16 c) {
    return __builtin_amdgcn_mfma_f32_32x32x16_bf16(a, b, c, 0, 0, 0);
}

__device__ inline float sum16v(const f32x16& v) {   // pairwise tree (pk-able)
    const f32x2* p = reinterpret_cast<const f32x2*>(&v);
    f32x2 q0 = p[0] + p[1], q1 = p[2] + p[3], q2 = p[4] + p[5], q3 = p[6] + p[7];
    f32x2 r0 = q0 + q1, r1 = q2 + q3;
    f32x2 t = r0 + r1;
    return t[0] + t[1];
}

// ------------------------------------------------------- QKV as three GEMMs
// z in {0,1,2}: Out_z[8192 x 1024] = X_z[8192 x 64] . Wz_flat[1024 x 64]^T
// (Wz[h][e][d] flat = row he, col d). 128x128 tile, K=64 single step,
// reg-staged fp32->bf16 cvt into XOR-swizzled LDS (out_gemm r6 read formula).
// z==3: Wo fp32->bf16 conversion (512 blocks, exact coverage).
__global__ __launch_bounds__(256) void qkv_gemm(
    const float* __restrict__ q_in, const float* __restrict__ k_in,
    const float* __restrict__ v_in,
    const float* __restrict__ Wq, const float* __restrict__ Wk,
    const float* __restrict__ Wv, const float* __restrict__ Wo,
    unsigned short* __restrict__ Qp, unsigned short* __restrict__ Kp,
    unsigned short* __restrict__ Vt, unsigned short* __restrict__ Wob) {
    const int z = blockIdx.z;
    const int t = threadIdx.x;

    if (z == 3) {   // Wo conversion: 512 blocks x 256 thr x 8 elems = 1M exact
        int id = blockIdx.x + 64 * blockIdx.y;
        int i = (id * 256 + t) * 8;
        float4 f0 = *reinterpret_cast<const float4*>(Wo + i);
        float4 f1 = *reinterpret_cast<const float4*>(Wo + i + 4);
        uint4 h;
        h.x = cvt_pk_bf16(f0.x, f0.y); h.y = cvt_pk_bf16(f0.z, f0.w);
        h.z = cvt_pk_bf16(f1.x, f1.y); h.w = cvt_pk_bf16(f1.z, f1.w);
        *reinterpret_cast<uint4*>(Wob + i) = h;
        return;
    }

    const float* X = (z == 0) ? q_in : (z == 1) ? k_in : v_in;
    const float* W = (z == 0) ? Wq : (z == 1) ? Wk : Wv;
    const int mb = blockIdx.x * 128;     // global s-row base
    const int nb = blockIdx.y * 128;     // global he base
    const int w = t >> 6, l = t & 63, lr = l & 15, lg = l >> 4;
    const int wr = (w >> 1) * 64, wc = (w & 1) * 64;

    __shared__ char XsB[16384];   // [128 rows][64 cols] bf16, 16B-seg XOR swizzle
    __shared__ char WsB[16384];

    // stage + convert: thread i-loop covers 128 rows x 8 segs
#pragma unroll
    for (int i = 0; i < 4; ++i) {
        int idx = t + i * 256;           // 0..1023
        int r = idx >> 3, sg = idx & 7;
        const float* xp = X + (size_t)(mb + r) * 64 + sg * 8;
        float4 f0 = *reinterpret_cast<const float4*>(xp);
        float4 f1 = *reinterpret_cast<const float4*>(xp + 4);
        uint4 hx;
        hx.x = cvt_pk_bf16(f0.x, f0.y); hx.y = cvt_pk_bf16(f0.z, f0.w);
        hx.z = cvt_pk_bf16(f1.x, f1.y); hx.w = cvt_pk_bf16(f1.z, f1.w);
        *reinterpret_cast<uint4*>(XsB + ((r * 128 + sg * 16) ^ ((r & 7) << 4))) = hx;
        const float* wp = W + (size_t)(nb + r) * 64 + sg * 8;
        float4 g0 = *reinterpret_cast<const float4*>(wp);
        float4 g1 = *reinterpret_cast<const float4*>(wp + 4);
        uint4 hw;
        hw.x = cvt_pk_bf16(g0.x, g0.y); hw.y = cvt_pk_bf16(g0.z, g0.w);
        hw.z = cvt_pk_bf16(g1.x, g1.y); hw.w = cvt_pk_bf16(g1.z, g1.w);
        *reinterpret_cast<uint4*>(WsB + ((r * 128 + sg * 16) ^ ((r & 7) << 4))) = hw;
    }
    __syncthreads();

    f32x4 acc[4][4];
#pragma unroll
    for (int mi = 0; mi < 4; ++mi)
#pragma unroll
        for (int ni = 0; ni < 4; ++ni) acc[mi][ni] = f32x4{0.f, 0.f, 0.f, 0.f};

    const int sx = (lr & 7) << 4;
#pragma unroll
    for (int kk = 0; kk < 2; ++kk) {
        const int cb = kk * 64 + lg * 16;
        bf16x8 af[4], bf[4];
#pragma unroll
        for (int mi = 0; mi < 4; ++mi)
            af[mi] = *reinterpret_cast<const bf16x8*>(
                XsB + (((wr + mi * 16 + lr) * 128 + cb) ^ sx));
#pragma unroll
        for (int ni = 0; ni < 4; ++ni)
            bf[ni] = *reinterpret_cast<const bf16x8*>(
                WsB + (((wc + ni * 16 + lr) * 128 + cb) ^ sx));
        if (z < 2) {   // C[he][s]: rows = W-rows (4lg+j), cols = X-rows (lr)
#pragma unroll
            for (int mi = 0; mi < 4; ++mi)
#pragma unroll
                for (int ni = 0; ni < 4; ++ni)
                    acc[mi][ni] = mfma16(bf[ni], af[mi], acc[mi][ni]);
        } else {       // C[s][he]: rows = X-rows (4lg+j), cols = W-rows (lr)
#pragma unroll
            for (int mi = 0; mi < 4; ++mi)
#pragma unroll
                for (int ni = 0; ni < 4; ++ni)
                    acc[mi][ni] = mfma16(af[mi], bf[ni], acc[mi][ni]);
        }
    }

    const int h = (nb + wc) >> 6;   // he quad never crosses a 64-boundary
    if (z < 2) {
        unsigned short* Out = (z == 0) ? Qp : Kp;
        const float sc = (z == 0) ? QSCALE : 1.0f;
#pragma unroll
        for (int mi = 0; mi < 4; ++mi) {
            int srow = mb + wr + mi * 16 + lr;
            int b = srow >> 11, s = srow & 2047;
            size_t base = (size_t)(b * 16 + h) * 131072 + (size_t)s * 64;
#pragma unroll
            for (int ni = 0; ni < 4; ++ni) {
                int e = ni * 16 + lg * 4;
                *reinterpret_cast<uint2*>(&Out[base + e]) =
                    pack4(acc[mi][ni][0] * sc, acc[mi][ni][1] * sc,
                          acc[mi][ni][2] * sc, acc[mi][ni][3] * sc);
            }
        }
    } else {
#pragma unroll
        for (int mi = 0; mi < 4; ++mi) {
            int srow = mb + wr + mi * 16 + lg * 4;
            int b = srow >> 11, s = srow & 2047;
            size_t base = (size_t)(b * 16 + h) * 131072;
#pragma unroll
            for (int ni = 0; ni < 4; ++ni) {
                int e = ni * 16 + lr;
                *reinterpret_cast<uint2*>(&Vt[base + (size_t)e * 2048 + s]) =
                    pack4(acc[mi][ni][0], acc[mi][ni][1],
                          acc[mi][ni][2], acc[mi][ni][3]);
            }
        }
    }
}

// ------------------------------------------------------------ flash attention
// (r6/r8 structure, unchanged: coalesced row-major staging w/ XOR pre-swizzled
// source; conflicts measured free, gather staging measured bad.)
__global__ __launch_bounds__(256, 4) void attn_kernel(
    const unsigned short* __restrict__ Qp, const unsigned short* __restrict__ Kp,
    const unsigned short* __restrict__ Vt, unsigned short* __restrict__ Xb) {
    const int id = blockIdx.x + 16 * blockIdx.y;
    const int bh = id & 63;              // id%8 = bh%8 -> per-XCD head grouping
    const int qx = id >> 6;
    const int b = bh >> 4, h = bh & 15;
    const int t = threadIdx.x;
    const int w = t >> 6, l = t & 63;
    const int lo = l & 31, hi = l >> 5;
    const int qw = qx * 128 + w * 32;

    __shared__ unsigned short Kbuf[2][4096];   // [64 rows][64 cols], swizzled segs
    __shared__ unsigned short Vbuf[2][4096];   // [64 e-rows][64 k-cols], swizzled

    bf16x8 bq[4];
    {
        const unsigned short* qptr = Qp + ((size_t)bh * 2048 + qw + lo) * 64 + hi * 8;
#pragma unroll
        for (int ds = 0; ds < 4; ++ds)
            bq[ds] = *reinterpret_cast<const bf16x8*>(qptr + ds * 16);
    }

    f32x16 oacc0, oacc1;
#pragma unroll
    for (int r = 0; r < 16; ++r) { oacc0[r] = 0.f; oacc1[r] = 0.f; }
    float lsum = 0.f;

    const unsigned short* kbase = Kp + (size_t)bh * 2048 * 64;
    const unsigned short* vbase = Vt + (size_t)bh * 64 * 2048;

    const int rr = l >> 3;              // 0..7
    const int sp = (l & 7) ^ rr;        // pre-swizzled segment
    const int rb = w * 16;              // wave's 16-row slice

#pragma unroll
    for (int i = 0; i < 2; ++i) {
        int r = rb + i * 8 + rr;
        __builtin_amdgcn_global_load_lds(
            (const g_u32*)(kbase + (size_t)r * 64 + sp * 8),
            (l_u32*)(&Kbuf[0][(rb + i * 8) * 64]), 16, 0, 0);
        __builtin_amdgcn_global_load_lds(
            (const g_u32*)(vbase + (size_t)r * 2048 + sp * 8),
            (l_u32*)(&Vbuf[0][(rb + i * 8) * 64]), 16, 0, 0);
    }
    __syncthreads();

    const int swz = (lo & 7) << 4;

    for (int kt = 0; kt < 32; ++kt) {
        const int cur = kt & 1;
        if (kt < 31) {
#pragma unroll
            for (int i = 0; i < 2; ++i) {
                int r = rb + i * 8 + rr;
                __builtin_amdgcn_global_load_lds(
                    (const g_u32*)(kbase + (size_t)((kt + 1) * 64 + r) * 64 + sp * 8),
                    (l_u32*)(&Kbuf[cur ^ 1][(rb + i * 8) * 64]), 16, 0, 0);
                __builtin_amdgcn_global_load_lds(
                    (const g_u32*)(vbase + (size_t)r * 2048 + (kt + 1) * 64 + sp * 8),
                    (l_u32*)(&Vbuf[cur ^ 1][(rb + i * 8) * 64]), 16, 0, 0);
            }
        }

        const char* kb = (const char*)Kbuf[cur];
        const char* vb = (const char*)Vbuf[cur];

#pragma unroll
        for (int half = 0; half < 2; ++half) {
            f32x16 s;
#pragma unroll
            for (int r = 0; r < 16; ++r) s[r] = 0.f;
            const char* krow = kb + (lo + 32 * half) * 128;
            __builtin_amdgcn_s_setprio(1);
#pragma unroll
            for (int ds = 0; ds < 4; ++ds) {
                bf16x8 ka = *reinterpret_cast<const bf16x8*>(krow + ((32 * ds + 16 * hi) ^ swz));
                s = mfma32(ka, bq[ds], s);
            }
            __builtin_amdgcn_s_setprio(0);

#pragma unroll
            for (int r = 0; r < 16; ++r) s[r] = __builtin_amdgcn_exp2f(s[r]);
            lsum += sum16v(s);

#pragma unroll
            for (int ks2 = 0; ks2 < 2; ++ks2) {
                const int bb = ks2 * 8;
                unsigned w0 = cvt_pk_bf16(s[bb + 0], s[bb + 1]);
                unsigned w1 = cvt_pk_bf16(s[bb + 2], s[bb + 3]);
                unsigned w2 = cvt_pk_bf16(s[bb + 4], s[bb + 5]);
                unsigned w3 = cvt_pk_bf16(s[bb + 6], s[bb + 7]);
                asm("v_permlane32_swap_b32 %0, %1" : "+v"(w0), "+v"(w2));
                asm("v_permlane32_swap_b32 %0, %1" : "+v"(w1), "+v"(w3));
                union { unsigned u[4]; bf16x8 v; } pa;
                pa.u[0] = w0; pa.u[1] = w1; pa.u[2] = w2; pa.u[3] = w3;
                int c = (32 * (half * 2 + ks2) + 16 * hi) ^ swz;
                bf16x8 v0 = *reinterpret_cast<const bf16x8*>(vb + lo * 128 + c);
                bf16x8 v1 = *reinterpret_cast<const bf16x8*>(vb + (lo + 32) * 128 + c);
                __builtin_amdgcn_s_setprio(1);
                oacc0 = mfma32(pa.v, v0, oacc0);
                oacc1 = mfma32(pa.v, v1, oacc1);
                __builtin_amdgcn_s_setprio(0);
            }
        }
        __syncthreads();
    }

    lsum += __shfl_xor(lsum, 32);
    const size_t rowbase = (size_t)b * 2048 * 1024 + (size_t)h * 64;
#pragma unroll
    for (int r = 0; r < 16; ++r) {
        int ql = (r & 3) + 8 * (r >> 2) + 4 * hi;
        float inv = 1.0f / __shfl(lsum, ql);
        unsigned short* dst = Xb + rowbase + (size_t)(qw + ql) * 1024;
        dst[lo] = f2bf1(oacc0[r] * inv);
        dst[lo + 32] = f2bf1(oacc1[r] * inv);
    }
}

// ------------------------------------------------------------- output GEMM
// (r6 structure, unchanged.)
__global__ __launch_bounds__(256) void out_gemm(
    const unsigned short* __restrict__ Xb, const unsigned short* __restrict__ Wob,
    float* __restrict__ out) {
    const int wg = blockIdx.x + 8 * blockIdx.y;   // 0..511
    const int xcd = wg & 7, k2 = wg >> 3;         // id%8 XCD round-robin
    const int mb = (xcd * 8 + (k2 & 7)) * 128;
    const int nb = (k2 >> 3) * 128;
    const int t = threadIdx.x;
    const int w = t >> 6, l = t & 63, lr = l & 15, lg = l >> 4;
    const int wr = (w >> 1) * 64, wc = (w & 1) * 64;

    __shared__ unsigned short As[2][128 * 64];
    __shared__ unsigned short Bs[2][128 * 64];

    f32x4 acc[4][4];
#pragma unroll
    for (int mi = 0; mi < 4; ++mi)
#pragma unroll
        for (int ni = 0; ni < 4; ++ni) acc[mi][ni] = f32x4{0.f, 0.f, 0.f, 0.f};

    const int rr = l >> 3;
    const int sp = (l & 7) ^ rr;        // pre-swizzled 16B segment
    const int swz = (lr & 7) << 4;

#pragma unroll
    for (int i = 0; i < 4; ++i) {
        int r = w * 32 + i * 8 + rr;
        __builtin_amdgcn_global_load_lds(
            (const g_u32*)(Xb + (size_t)(mb + r) * 1024 + sp * 8),
            (l_u32*)(&As[0][(w * 32 + i * 8) * 64]), 16, 0, 0);
        __builtin_amdgcn_global_load_lds(
            (const g_u32*)(Wob + (size_t)(nb + r) * 1024 + sp * 8),
            (l_u32*)(&Bs[0][(w * 32 + i * 8) * 64]), 16, 0, 0);
    }
    __syncthreads();

    for (int kt = 0; kt < 16; ++kt) {
        const int cur = kt & 1;
        if (kt < 15) {
#pragma unroll
            for (int i = 0; i < 4; ++i) {
                int r = w * 32 + i * 8 + rr;
                __builtin_amdgcn_global_load_lds(
                    (const g_u32*)(Xb + (size_t)(mb + r) * 1024 + (kt + 1) * 64 + sp * 8),
                    (l_u32*)(&As[cur ^ 1][(w * 32 + i * 8) * 64]), 16, 0, 0);
                __builtin_amdgcn_global_load_lds(
                    (const g_u32*)(Wob + (size_t)(nb + r) * 1024 + (kt + 1) * 64 + sp * 8),
                    (l_u32*)(&Bs[cur ^ 1][(w * 32 + i * 8) * 64]), 16, 0, 0);
            }
        }

        const char* ab = (const char*)As[cur];
        const char* bbp = (const char*)Bs[cur];
#pragma unroll
        for (int kk = 0; kk < 2; ++kk) {
            const int cb = (kk * 64 + lg * 16) ^ swz;
            bf16x8 af[4], bf[4];
#pragma unroll
            for (int mi = 0; mi < 4; ++mi)
                af[mi] = *reinterpret_cast<const bf16x8*>(ab + (wr + mi * 16 + lr) * 128 + cb);
#pragma unroll
            for (int ni = 0; ni < 4; ++ni)
                bf[ni] = *reinterpret_cast<const bf16x8*>(bbp + (wc + ni * 16 + lr) * 128 + cb);
            __builtin_amdgcn_s_setprio(1);
#pragma unroll
            for (int mi = 0; mi < 4; ++mi)
#pragma unroll
                for (int ni = 0; ni < 4; ++ni)
                    acc[mi][ni] = mfma16(bf[ni], af[mi], acc[mi][ni]);
            __builtin_amdgcn_s_setprio(0);
        }
        __syncthreads();
    }

#pragma unroll
    for (int mi = 0; mi < 4; ++mi) {
        const size_t row = (size_t)(mb + wr + mi * 16 + lr);
#pragma unroll
        for (int ni = 0; ni < 4; ++ni) {
            float4 o;
            o.x = acc[mi][ni][0]; o.y = acc[mi][ni][1];
            o.z = acc[mi][ni][2]; o.w = acc[mi][ni][3];
            *reinterpret_cast<float4*>(&out[row * 1024 + nb + wc + ni * 16 + lg * 4]) = o;
        }
    }
}

// ---------------------------------------------------------------- launcher
extern "C" void kernel_launch(void* const* d_in, const int* in_sizes, int n_in,
                              void* d_out, int out_size, void* d_ws, size_t ws_size,
                              hipStream_t stream) {
    (void)in_sizes; (void)n_in; (void)out_size; (void)ws_size;
    const float* query = (const float*)d_in[0];
    const float* key   = (const float*)d_in[1];
    const float* value = (const float*)d_in[2];
    const float* Wq = (const float*)d_in[3];
    const float* Wk = (const float*)d_in[4];
    const float* Wv = (const float*)d_in[5];
    const float* Wo = (const float*)d_in[6];
    float* out = (float*)d_out;

    char* ws = (char*)d_ws;
    unsigned short* Qp  = (unsigned short*)(ws);
    unsigned short* Kp  = (unsigned short*)(ws + (size_t)16 * 1024 * 1024);
    unsigned short* Vt  = (unsigned short*)(ws + (size_t)32 * 1024 * 1024);
    unsigned short* Xb  = (unsigned short*)(ws + (size_t)48 * 1024 * 1024);
    unsigned short* Wob = (unsigned short*)(ws + (size_t)64 * 1024 * 1024);

    hipLaunchKernelGGL(qkv_gemm, dim3(64, 8, 4), dim3(256), 0, stream,
                       query, key, value, Wq, Wk, Wv, Wo, Qp, Kp, Vt, Wob);
    hipLaunchKernelGGL(attn_kernel, dim3(16, 64), dim3(256), 0, stream,
                       Qp, Kp, Vt, Xb);
    hipLaunchKernelGGL(out_gemm, dim3(8, 64), dim3(256), 0, stream,
                       Xb, Wob, out);
}